// Round 10
// baseline (334.875 us; speedup 1.0000x reference)
//
#include <hip/hip_runtime.h>

#define QMIN_V 0.1f
#define EPS_V  1e-7f

typedef int iv4 __attribute__((ext_vector_type(4)));     // clang vector: OK for nontemporal builtins
typedef float fv4 __attribute__((ext_vector_type(4)));

// ---------------------------------------------------------------------------
// ws layout (16B aligned):
//   float4 mdq[np]   (mx,my,mz,mq)  -- winner payload, mq==0 => invalid
//   float4 xpt[nn]   (x0,x1,x2,bitcast(parent_target))    [optional]
//   u64    packed[np] (bits(beta_mail)<<32 | edge_idx)
//   float  accum[nn]
// ---------------------------------------------------------------------------

// Fused init: zero packed+accum, build xpt table.
template <int USE_XPT>
__global__ void prep_kernel(const float* __restrict__ x,
                            const int* __restrict__ pt,
                            float4* __restrict__ xpt,
                            unsigned long long* __restrict__ packed,
                            float* __restrict__ accum, int np, int nn) {
    int i = blockIdx.x * blockDim.x + threadIdx.x;
    if (i < np) packed[i] = 0ULL;
    if (i < nn) {
        accum[i] = 0.0f;
        if (USE_XPT)
            xpt[i] = make_float4(x[3 * i + 0], x[3 * i + 1], x[3 * i + 2],
                                 __int_as_float(pt[i]));
    }
}

// ---------------------------------------------------------------------------
// Pass A: per-edge label -> per-particle packed atomicMax (rare hit path).
// 8 edges/iter; edges prefetched 2 iters ahead, pt-gathers 1 iter ahead.
// ---------------------------------------------------------------------------
__global__ __launch_bounds__(256, 3)
void passA_kernel(const int* __restrict__ en, const int* __restrict__ ep,
                  const float* __restrict__ beta,
                  const int* __restrict__ isTrack,
                  const int* __restrict__ pt,
                  const int* __restrict__ pidx,
                  const int* __restrict__ pclass,
                  unsigned long long* __restrict__ packed,
                  int np, int ne8, int ne) {
    extern __shared__ int s_pidx[];
    for (int j = threadIdx.x; j < np; j += blockDim.x) s_pidx[j] = pidx[j];
    __syncthreads();

    const int tid = blockIdx.x * blockDim.x + threadIdx.x;
    const int stride = gridDim.x * blockDim.x;
    const iv4* en4 = reinterpret_cast<const iv4*>(en);
    const iv4* ep4 = reinterpret_cast<const iv4*>(ep);

    if (tid < ne8) {
        // stage registers: A = compute, B = gathers in flight, C = edge prefetch
        int iB = (tid + stride < ne8) ? (tid + stride) : tid;
        iv4 eA0 = __builtin_nontemporal_load(&en4[2 * tid]);
        iv4 eA1 = __builtin_nontemporal_load(&en4[2 * tid + 1]);
        iv4 pA0 = __builtin_nontemporal_load(&ep4[2 * tid]);
        iv4 pA1 = __builtin_nontemporal_load(&ep4[2 * tid + 1]);
        iv4 eB0 = __builtin_nontemporal_load(&en4[2 * iB]);
        iv4 eB1 = __builtin_nontemporal_load(&en4[2 * iB + 1]);
        iv4 pB0 = __builtin_nontemporal_load(&ep4[2 * iB]);
        iv4 pB1 = __builtin_nontemporal_load(&ep4[2 * iB + 1]);

        int nA[8], piA[8], tA[8], qA[8];
#pragma unroll
        for (int k = 0; k < 4; ++k) { nA[k] = eA0[k]; nA[k + 4] = eA1[k];
                                      piA[k] = pA0[k]; piA[k + 4] = pA1[k]; }
#pragma unroll
        for (int k = 0; k < 8; ++k) tA[k] = pt[nA[k]];
#pragma unroll
        for (int k = 0; k < 8; ++k) qA[k] = s_pidx[piA[k]];

        for (int i = tid; i < ne8; i += stride) {
            int iC = (i + 2 * stride < ne8) ? (i + 2 * stride) : tid;
            iv4 eC0 = __builtin_nontemporal_load(&en4[2 * iC]);
            iv4 eC1 = __builtin_nontemporal_load(&en4[2 * iC + 1]);
            iv4 pC0 = __builtin_nontemporal_load(&ep4[2 * iC]);
            iv4 pC1 = __builtin_nontemporal_load(&ep4[2 * iC + 1]);

            int nB[8], piB[8], tB[8], qB[8];
#pragma unroll
            for (int k = 0; k < 4; ++k) { nB[k] = eB0[k]; nB[k + 4] = eB1[k];
                                          piB[k] = pB0[k]; piB[k + 4] = pB1[k]; }
#pragma unroll
            for (int k = 0; k < 8; ++k) tB[k] = pt[nB[k]];
#pragma unroll
            for (int k = 0; k < 8; ++k) qB[k] = s_pidx[piB[k]];

            // compute stage A (edge indices 8*i + k); hit density ~1.8e-4
#pragma unroll
            for (int k = 0; k < 8; ++k) {
                if (tA[k] == qA[k]) {
                    float b = beta[nA[k]];
                    int pc = pclass[piA[k]];
                    float bm = (pc < 2) ? b : b * (float)isTrack[nA[k]];
                    if (bm > 0.0f) {
                        unsigned long long key =
                            ((unsigned long long)__float_as_uint(bm) << 32) |
                            (unsigned int)(8 * i + k);
                        atomicMax(&packed[piA[k]], key);
                    }
                }
            }
            // shift pipeline
            eB0 = eC0; eB1 = eC1; pB0 = pC0; pB1 = pC1;
#pragma unroll
            for (int k = 0; k < 8; ++k) { nA[k] = nB[k]; piA[k] = piB[k];
                                          tA[k] = tB[k]; qA[k] = qB[k]; }
        }
    }
    // scalar tail
    for (int e = ne8 * 8 + tid; e < ne; e += stride) {
        int n = en[e];
        int p = ep[e];
        if (pt[n] == pidx[p]) {
            float b = beta[n];
            int pc = pclass[p];
            float bm = (pc < 2) ? b : b * (float)isTrack[n];
            if (bm > 0.0f) {
                unsigned long long key =
                    ((unsigned long long)__float_as_uint(bm) << 32) |
                    (unsigned int)e;
                atomicMax(&packed[p], key);
            }
        }
    }
}

// ---------------------------------------------------------------------------
// Pass P: unpack winner, emit mdq[p] = (mx,my,mz,mq); mq==0 marks invalid.
// ---------------------------------------------------------------------------
__global__ void passP_kernel(const unsigned long long* __restrict__ packed,
                             const int* __restrict__ en,
                             const float* __restrict__ beta,
                             const float* __restrict__ x,
                             float4* __restrict__ mdq, int np) {
    int p = blockIdx.x * blockDim.x + threadIdx.x;
    if (p >= np) return;
    unsigned long long key = packed[p];
    unsigned int bm_bits = (unsigned int)(key >> 32);
    float4 md = make_float4(0.0f, 0.0f, 0.0f, 0.0f);
    if (bm_bits != 0u) {  // valid <=> max beta_mail > 0
        int e = (int)(key & 0xffffffffULL);
        int n = en[e];
        float b = beta[n];
        float cb = fminf(fmaxf(b, EPS_V), 1.0f - EPS_V);
        float a = atanhf(cb);
        md.x = x[3 * n + 0];
        md.y = x[3 * n + 1];
        md.z = x[3 * n + 2];
        md.w = a * a + QMIN_V;
    }
    mdq[p] = md;
}

// ---------------------------------------------------------------------------
// Pass B: branchless per-edge potential -> predicated atomicAdd.
// v == 0 identically when mq == 0, so gathers are unconditional.
// 4 edges/iter; edges prefetched 2 iters ahead, gathers 1 iter ahead.
// ---------------------------------------------------------------------------
template <int USE_XPT>
__global__ __launch_bounds__(256, 3)
void passB_kernel(const int* __restrict__ en, const int* __restrict__ ep,
                  const float* __restrict__ x, const int* __restrict__ pt,
                  const float4* __restrict__ xpt,
                  const float4* __restrict__ mdq,
                  const int* __restrict__ pidx,
                  float* __restrict__ accum,
                  int np, int ne4, int ne) {
    extern __shared__ int s_pidx[];
    for (int j = threadIdx.x; j < np; j += blockDim.x) s_pidx[j] = pidx[j];
    __syncthreads();

    const int tid = blockIdx.x * blockDim.x + threadIdx.x;
    const int stride = gridDim.x * blockDim.x;
    const iv4* en4 = reinterpret_cast<const iv4*>(en);
    const iv4* ep4 = reinterpret_cast<const iv4*>(ep);

    if (tid < ne4) {
        int iB = (tid + stride < ne4) ? (tid + stride) : tid;
        iv4 eA = __builtin_nontemporal_load(&en4[tid]);
        iv4 pA = __builtin_nontemporal_load(&ep4[tid]);
        iv4 eB = __builtin_nontemporal_load(&en4[iB]);
        iv4 pB = __builtin_nontemporal_load(&ep4[iB]);

        float4 mA[4], xA[4];
        int qA[4];
#pragma unroll
        for (int k = 0; k < 4; ++k) mA[k] = mdq[pA[k]];
#pragma unroll
        for (int k = 0; k < 4; ++k) {
            int n = eA[k];
            if (USE_XPT) xA[k] = xpt[n];
            else xA[k] = make_float4(x[3 * n], x[3 * n + 1], x[3 * n + 2],
                                     __int_as_float(pt[n]));
        }
#pragma unroll
        for (int k = 0; k < 4; ++k) qA[k] = s_pidx[pA[k]];

        for (int i = tid; i < ne4; i += stride) {
            int iC = (i + 2 * stride < ne4) ? (i + 2 * stride) : tid;
            iv4 eC = __builtin_nontemporal_load(&en4[iC]);
            iv4 pC = __builtin_nontemporal_load(&ep4[iC]);

            float4 mB[4], xB[4];
            int qB[4];
#pragma unroll
            for (int k = 0; k < 4; ++k) mB[k] = mdq[pB[k]];
#pragma unroll
            for (int k = 0; k < 4; ++k) {
                int n = eB[k];
                if (USE_XPT) xB[k] = xpt[n];
                else xB[k] = make_float4(x[3 * n], x[3 * n + 1], x[3 * n + 2],
                                         __int_as_float(pt[n]));
            }
#pragma unroll
            for (int k = 0; k < 4; ++k) qB[k] = s_pidx[pB[k]];

            // branchless compute of stage A
#pragma unroll
            for (int k = 0; k < 4; ++k) {
                float mq = mA[k].w;
                float dx = mA[k].x - xA[k].x;
                float dy = mA[k].y - xA[k].y;
                float dz = mA[k].z - xA[k].z;
                float d2 = dx * dx + dy * dy + dz * dz;
                float dist = sqrtf(d2);
                bool label = (__float_as_int(xA[k].w) == qA[k]);
                float v = label ? (3.0f * mq * d2)
                                : (fmaxf(2.0f - dist, 0.0f) * mq);
                if (v > 0.0f) atomicAdd(&accum[eA[k]], v);
            }
            // shift pipeline
            eA = eB; pA = pB; eB = eC; pB = pC;
#pragma unroll
            for (int k = 0; k < 4; ++k) { mA[k] = mB[k]; xA[k] = xB[k]; qA[k] = qB[k]; }
        }
    }
    // scalar tail
    for (int e = ne4 * 4 + tid; e < ne; e += stride) {
        int n = en[e];
        int p = ep[e];
        float4 md = mdq[p];
        float mq = md.w;
        float x0, x1, x2; int ptv;
        if (USE_XPT) {
            float4 xp = xpt[n];
            x0 = xp.x; x1 = xp.y; x2 = xp.z; ptv = __float_as_int(xp.w);
        } else {
            x0 = x[3 * n]; x1 = x[3 * n + 1]; x2 = x[3 * n + 2]; ptv = pt[n];
        }
        float dx = md.x - x0, dy = md.y - x1, dz = md.z - x2;
        float d2 = dx * dx + dy * dy + dz * dz;
        bool label = (ptv == pidx[p]);
        float v = label ? (3.0f * mq * d2)
                        : (fmaxf(2.0f - sqrtf(d2), 0.0f) * mq);
        if (v > 0.0f) atomicAdd(&accum[n], v);
    }
}

// Pass N: node_lv = q * (attract + repulse)
__global__ void passN_kernel(const float* __restrict__ beta,
                             const float* __restrict__ accum,
                             float* __restrict__ out, int nn) {
    int i = blockIdx.x * blockDim.x + threadIdx.x;
    if (i >= nn) return;
    float b = beta[i];
    float cb = fminf(fmaxf(b, EPS_V), 1.0f - EPS_V);
    float a = atanhf(cb);
    out[i] = (a * a + QMIN_V) * accum[i];
}

extern "C" void kernel_launch(void* const* d_in, const int* in_sizes, int n_in,
                              void* d_out, int out_size, void* d_ws, size_t ws_size,
                              hipStream_t stream) {
    const float* beta    = (const float*)d_in[0];
    const float* x       = (const float*)d_in[1];
    const int*   isTrack = (const int*)d_in[2];
    const int*   pt      = (const int*)d_in[3];
    const int*   pidx    = (const int*)d_in[4];
    const int*   pclass  = (const int*)d_in[5];
    const int*   en      = (const int*)d_in[6];
    const int*   ep      = (const int*)d_in[7];
    float* out = (float*)d_out;

    int nn = in_sizes[0];
    int np = in_sizes[4];
    int ne = in_sizes[6];

    // ws layout
    char* ws = (char*)d_ws;
    size_t off = 0;
    float4* mdq = (float4*)(ws + off); off += (size_t)np * 16;
    size_t xpt_off = off;
    size_t need_xpt = off + (size_t)nn * 16 + (size_t)np * 8 + (size_t)nn * 4;
    bool use_xpt = (ws_size >= need_xpt);
    float4* xpt = nullptr;
    if (use_xpt) { xpt = (float4*)(ws + xpt_off); off += (size_t)nn * 16; }
    unsigned long long* packed = (unsigned long long*)(ws + off); off += (size_t)np * 8;
    float* accum = (float*)(ws + off);

    int ne8 = ne / 8;
    int ne4 = ne / 4;
    int lds_bytes = np * (int)sizeof(int);
    int prep_blocks = ((nn > np ? nn : np) + 255) / 256;

    if (use_xpt)
        prep_kernel<1><<<prep_blocks, 256, 0, stream>>>(x, pt, xpt, packed,
                                                        accum, np, nn);
    else
        prep_kernel<0><<<prep_blocks, 256, 0, stream>>>(x, pt, xpt, packed,
                                                        accum, np, nn);
    passA_kernel<<<2048, 256, lds_bytes, stream>>>(en, ep, beta, isTrack, pt,
                                                   pidx, pclass, packed,
                                                   np, ne8, ne);
    passP_kernel<<<(np + 255) / 256, 256, 0, stream>>>(packed, en, beta, x,
                                                       mdq, np);
    if (use_xpt)
        passB_kernel<1><<<2048, 256, lds_bytes, stream>>>(en, ep, x, pt, xpt,
                                                          mdq, pidx, accum,
                                                          np, ne4, ne);
    else
        passB_kernel<0><<<2048, 256, lds_bytes, stream>>>(en, ep, x, pt, xpt,
                                                          mdq, pidx, accum,
                                                          np, ne4, ne);
    passN_kernel<<<(nn + 255) / 256, 256, 0, stream>>>(beta, accum, out, nn);
}

// Round 11
// 256.484 us; speedup vs baseline: 1.3056x; 1.3056x over previous
//
#include <hip/hip_runtime.h>

#define QMIN_V 0.1f
#define EPS_V  1e-7f

typedef int iv4 __attribute__((ext_vector_type(4)));

// ---------------------------------------------------------------------------
// ws layout (16B aligned):
//   float4 maxdata[np]  (mx,my,mz, bitcast(pidx))
//   float4 xpt[nn]      (x0,x1,x2, bitcast(parent_target))   [optional]
//   u64    packed[np]   (bits(beta_mail)<<32 | edge_idx)
//   float  mq[np]
//   float  accum[nn]
// ---------------------------------------------------------------------------

template <int USE_XPT>
__global__ void prep_kernel(const float* __restrict__ x,
                            const int* __restrict__ pt,
                            float4* __restrict__ xpt,
                            unsigned long long* __restrict__ packed,
                            float* __restrict__ accum, int np, int nn) {
    int i = blockIdx.x * blockDim.x + threadIdx.x;
    if (i < np) packed[i] = 0ULL;
    if (i < nn) {
        accum[i] = 0.0f;
        if (USE_XPT)
            xpt[i] = make_float4(x[3 * i + 0], x[3 * i + 1], x[3 * i + 2],
                                 __int_as_float(pt[i]));
    }
}

// ---------------------------------------------------------------------------
// Pass A (one-shot): each thread owns 8 contiguous edges, then exits.
// TLP comes from the block queue (no grid-stride serial chain).
// ---------------------------------------------------------------------------
__global__ void passA_kernel(const int* __restrict__ en, const int* __restrict__ ep,
                             const float* __restrict__ beta,
                             const int* __restrict__ isTrack,
                             const int* __restrict__ pt,
                             const int* __restrict__ pidx,
                             const int* __restrict__ pclass,
                             unsigned long long* __restrict__ packed,
                             int np, int ne) {
    extern __shared__ int s_pidx[];
    for (int j = threadIdx.x; j < np; j += blockDim.x) s_pidx[j] = pidx[j];
    __syncthreads();

    int tid = blockIdx.x * blockDim.x + threadIdx.x;
    int base = tid * 8;
    if (base >= ne) return;

    if (base + 8 <= ne) {
        const iv4* en4 = reinterpret_cast<const iv4*>(en);
        const iv4* ep4 = reinterpret_cast<const iv4*>(ep);
        iv4 e0 = __builtin_nontemporal_load(&en4[2 * tid]);
        iv4 e1 = __builtin_nontemporal_load(&en4[2 * tid + 1]);
        iv4 p0 = __builtin_nontemporal_load(&ep4[2 * tid]);
        iv4 p1 = __builtin_nontemporal_load(&ep4[2 * tid + 1]);
        int n[8], p[8], t[8], q[8];
#pragma unroll
        for (int k = 0; k < 4; ++k) { n[k] = e0[k]; n[k + 4] = e1[k];
                                      p[k] = p0[k]; p[k + 4] = p1[k]; }
#pragma unroll
        for (int k = 0; k < 8; ++k) t[k] = pt[n[k]];      // 8 independent gathers
#pragma unroll
        for (int k = 0; k < 8; ++k) q[k] = s_pidx[p[k]];  // LDS
#pragma unroll
        for (int k = 0; k < 8; ++k) {
            if (t[k] == q[k]) {                            // ~1.8e-4 density
                float b = beta[n[k]];
                int pc = pclass[p[k]];
                float bm = (pc < 2) ? b : b * (float)isTrack[n[k]];
                if (bm > 0.0f) {
                    unsigned long long key =
                        ((unsigned long long)__float_as_uint(bm) << 32) |
                        (unsigned int)(base + k);
                    atomicMax(&packed[p[k]], key);
                }
            }
        }
    } else {
        for (int e = base; e < ne; ++e) {
            int n = en[e];
            int p = ep[e];
            if (pt[n] == s_pidx[p]) {
                float b = beta[n];
                int pc = pclass[p];
                float bm = (pc < 2) ? b : b * (float)isTrack[n];
                if (bm > 0.0f) {
                    unsigned long long key =
                        ((unsigned long long)__float_as_uint(bm) << 32) |
                        (unsigned int)e;
                    atomicMax(&packed[p], key);
                }
            }
        }
    }
}

// ---------------------------------------------------------------------------
// Pass P: unpack winner; maxdata=(mx,my,mz,bitcast pidx), mq separate.
// ---------------------------------------------------------------------------
__global__ void passP_kernel(const unsigned long long* __restrict__ packed,
                             const int* __restrict__ en,
                             const float* __restrict__ beta,
                             const float* __restrict__ x,
                             const int* __restrict__ pidx,
                             float4* __restrict__ maxdata,
                             float* __restrict__ mq, int np) {
    int p = blockIdx.x * blockDim.x + threadIdx.x;
    if (p >= np) return;
    unsigned long long key = packed[p];
    unsigned int bm_bits = (unsigned int)(key >> 32);
    float mqv = 0.0f, mx = 0.0f, my = 0.0f, mz = 0.0f;
    if (bm_bits != 0u) {  // valid <=> max beta_mail > 0 (matches reference)
        int e = (int)(key & 0xffffffffULL);
        int n = en[e];
        float b = beta[n];
        float cb = fminf(fmaxf(b, EPS_V), 1.0f - EPS_V);
        float a = atanhf(cb);
        mqv = a * a + QMIN_V;
        mx = x[3 * n + 0];
        my = x[3 * n + 1];
        mz = x[3 * n + 2];
    }
    maxdata[p] = make_float4(mx, my, mz, __int_as_float(pidx[p]));
    mq[p] = mqv;
}

// ---------------------------------------------------------------------------
// Pass B (one-shot): each thread owns 4 contiguous edges.
// LDS mq reject (~78% of edges skip gathers); active path = 2 float4 gathers.
// ---------------------------------------------------------------------------
template <int USE_XPT>
__global__ void passB_kernel(const int* __restrict__ en, const int* __restrict__ ep,
                             const float* __restrict__ x, const int* __restrict__ pt,
                             const float4* __restrict__ xpt,
                             const float4* __restrict__ maxdata,
                             const float* __restrict__ mq,
                             float* __restrict__ accum,
                             int np, int ne) {
    extern __shared__ float s_mq[];
    for (int j = threadIdx.x; j < np; j += blockDim.x) s_mq[j] = mq[j];
    __syncthreads();

    int tid = blockIdx.x * blockDim.x + threadIdx.x;
    int base = tid * 4;
    if (base >= ne) return;

    if (base + 4 <= ne) {
        const iv4* en4 = reinterpret_cast<const iv4*>(en);
        const iv4* ep4 = reinterpret_cast<const iv4*>(ep);
        iv4 e = __builtin_nontemporal_load(&en4[tid]);
        iv4 p = __builtin_nontemporal_load(&ep4[tid]);
        float m[4];
#pragma unroll
        for (int k = 0; k < 4; ++k) m[k] = s_mq[p[k]];
        float4 md[4], xv[4];
#pragma unroll
        for (int k = 0; k < 4; ++k) {
            if (m[k] > 0.0f) {                      // ~22% density
                md[k] = maxdata[p[k]];
                if (USE_XPT) xv[k] = xpt[e[k]];
                else {
                    int n = e[k];
                    xv[k] = make_float4(x[3 * n], x[3 * n + 1], x[3 * n + 2],
                                        __int_as_float(pt[n]));
                }
            }
        }
#pragma unroll
        for (int k = 0; k < 4; ++k) {
            if (m[k] > 0.0f) {
                float dx = md[k].x - xv[k].x;
                float dy = md[k].y - xv[k].y;
                float dz = md[k].z - xv[k].z;
                float d2 = dx * dx + dy * dy + dz * dz;
                bool label = (__float_as_int(xv[k].w) == __float_as_int(md[k].w));
                float v = label ? (3.0f * m[k] * d2)
                                : (fmaxf(2.0f - sqrtf(d2), 0.0f) * m[k]);
                if (v > 0.0f) atomicAdd(&accum[e[k]], v);
            }
        }
    } else {
        for (int e = base; e < ne; ++e) {
            int n = en[e];
            int p = ep[e];
            float m = s_mq[p];
            if (m > 0.0f) {
                float4 md = maxdata[p];
                float x0, x1, x2; int ptv;
                if (USE_XPT) {
                    float4 xp = xpt[n];
                    x0 = xp.x; x1 = xp.y; x2 = xp.z; ptv = __float_as_int(xp.w);
                } else {
                    x0 = x[3 * n]; x1 = x[3 * n + 1]; x2 = x[3 * n + 2];
                    ptv = pt[n];
                }
                float dx = md.x - x0, dy = md.y - x1, dz = md.z - x2;
                float d2 = dx * dx + dy * dy + dz * dz;
                bool label = (ptv == __float_as_int(md.w));
                float v = label ? (3.0f * m * d2)
                                : (fmaxf(2.0f - sqrtf(d2), 0.0f) * m);
                if (v > 0.0f) atomicAdd(&accum[n], v);
            }
        }
    }
}

// Pass N: node_lv = q * (attract + repulse)
__global__ void passN_kernel(const float* __restrict__ beta,
                             const float* __restrict__ accum,
                             float* __restrict__ out, int nn) {
    int i = blockIdx.x * blockDim.x + threadIdx.x;
    if (i >= nn) return;
    float b = beta[i];
    float cb = fminf(fmaxf(b, EPS_V), 1.0f - EPS_V);
    float a = atanhf(cb);
    out[i] = (a * a + QMIN_V) * accum[i];
}

extern "C" void kernel_launch(void* const* d_in, const int* in_sizes, int n_in,
                              void* d_out, int out_size, void* d_ws, size_t ws_size,
                              hipStream_t stream) {
    const float* beta    = (const float*)d_in[0];
    const float* x       = (const float*)d_in[1];
    const int*   isTrack = (const int*)d_in[2];
    const int*   pt      = (const int*)d_in[3];
    const int*   pidx    = (const int*)d_in[4];
    const int*   pclass  = (const int*)d_in[5];
    const int*   en      = (const int*)d_in[6];
    const int*   ep      = (const int*)d_in[7];
    float* out = (float*)d_out;

    int nn = in_sizes[0];
    int np = in_sizes[4];
    int ne = in_sizes[6];

    // ws layout
    char* ws = (char*)d_ws;
    size_t off = 0;
    float4* maxdata = (float4*)(ws + off); off += (size_t)np * 16;
    size_t xpt_off = off;
    size_t need_xpt = off + (size_t)nn * 16 + (size_t)np * 8 + (size_t)np * 4
                      + (size_t)nn * 4;
    bool use_xpt = (ws_size >= need_xpt);
    float4* xpt = nullptr;
    if (use_xpt) { xpt = (float4*)(ws + xpt_off); off += (size_t)nn * 16; }
    unsigned long long* packed = (unsigned long long*)(ws + off); off += (size_t)np * 8;
    float* mq = (float*)(ws + off); off += (size_t)np * 4;
    float* accum = (float*)(ws + off);

    int lds_bytes = np * (int)sizeof(int);
    int prep_blocks = ((nn > np ? nn : np) + 255) / 256;

    // one-shot grids: 8 edges/thread (A), 4 edges/thread (B)
    int thrA = (ne + 7) / 8;
    int blkA = (thrA + 255) / 256;
    int thrB = (ne + 3) / 4;
    int blkB = (thrB + 255) / 256;

    if (use_xpt)
        prep_kernel<1><<<prep_blocks, 256, 0, stream>>>(x, pt, xpt, packed,
                                                        accum, np, nn);
    else
        prep_kernel<0><<<prep_blocks, 256, 0, stream>>>(x, pt, xpt, packed,
                                                        accum, np, nn);
    passA_kernel<<<blkA, 256, lds_bytes, stream>>>(en, ep, beta, isTrack, pt,
                                                   pidx, pclass, packed, np, ne);
    passP_kernel<<<(np + 255) / 256, 256, 0, stream>>>(packed, en, beta, x,
                                                       pidx, maxdata, mq, np);
    if (use_xpt)
        passB_kernel<1><<<blkB, 256, lds_bytes, stream>>>(en, ep, x, pt, xpt,
                                                          maxdata, mq, accum,
                                                          np, ne);
    else
        passB_kernel<0><<<blkB, 256, lds_bytes, stream>>>(en, ep, x, pt, xpt,
                                                          maxdata, mq, accum,
                                                          np, ne);
    passN_kernel<<<(nn + 255) / 256, 256, 0, stream>>>(beta, accum, out, nn);
}